// Round 5
// baseline (1166.467 us; speedup 1.0000x reference)
//
#include <hip/hip_runtime.h>
#include <math.h>

// MEASUREMENT ROUND 2 (de-confounded): 8 cold passes. Pass 0 = the real
// half-row; passes 1..7 read OTHER half-rows ((bid + p*prot) & 8191), so every
// pass cycles the full 524 MB working set -> reuse distance > 256 MB L3 ->
// LRU thrash -> cold HBM streaming on every pass. Dummy sums are scaled by a
// runtime 0.0f so the compiler cannot elide them and the result is exact.
// K_cold (single-pass streaming time) = probe_dur / 8, read directly from
// rocprof top-5. FETCH_SIZE ~ 4.2e6 KB confirms coldness.

#define NCLS 32000
#define NROW 4096
#define HALF4 4000   // float4 per half-row
#define HALFN 16000  // floats per half-row

typedef float f4 __attribute__((ext_vector_type(4)));

__device__ __forceinline__ float exp4sum(f4 v) {
    return (__expf(v.x) + __expf(v.y)) + (__expf(v.z) + __expf(v.w));
}

__device__ __forceinline__ float sweep_half(const f4* __restrict__ base, int tid) {
    float s0 = 0.f, s1 = 0.f, s2 = 0.f, s3 = 0.f;
    int i = tid;
    for (; i + 768 < HALF4; i += 1024) {
        f4 a = __builtin_nontemporal_load(base + i);
        f4 c = __builtin_nontemporal_load(base + i + 256);
        f4 d = __builtin_nontemporal_load(base + i + 512);
        f4 e = __builtin_nontemporal_load(base + i + 768);
        s0 += exp4sum(a);
        s1 += exp4sum(c);
        s2 += exp4sum(d);
        s3 += exp4sum(e);
    }
    for (; i < HALF4; i += 256) {
        s0 += exp4sum(__builtin_nontemporal_load(base + i));
    }
    return (s0 + s1) + (s2 + s3);
}

// d_ws layout: [0,4096) xt_arr ; [4096,4096+8192) partial sums
__global__ __launch_bounds__(256) void ce_probe8(const float* __restrict__ pred,
                                                 const int* __restrict__ target,
                                                 float* __restrict__ ws,
                                                 int prot, float zscale) {
    const int bid = blockIdx.x;
    const int b = bid >> 1;
    const int half = bid & 1;
    const int tid = threadIdx.x;

    const float* row = pred + (size_t)b * NCLS;
    const f4* own = reinterpret_cast<const f4*>(row) + half * HALF4;

    const int t = target[b];
    if (tid == 0 && (unsigned)(t - half * HALFN) < (unsigned)HALFN) {
        ws[b] = row[t];
    }

    // Pass 0: the real half-row.
    float s = sweep_half(own, tid);

    // Passes 1..7: cold dummy half-rows, contribution scaled by runtime 0.0f.
    float sd = 0.f;
    for (int p = 1; p < 8; ++p) {
        const int h = (bid + p * prot) & 8191;
        const f4* base = reinterpret_cast<const f4*>(pred + (size_t)h * HALFN);
        sd += sweep_half(base, tid);
    }
    s += zscale * sd;

    for (int off = 32; off; off >>= 1) s += __shfl_down(s, off, 64);

    __shared__ float ss[4];
    if ((tid & 63) == 0) ss[tid >> 6] = s;
    __syncthreads();
    if (tid == 0) {
        ws[NROW + bid] = (ss[0] + ss[1]) + (ss[2] + ss[3]);
    }
}

__global__ __launch_bounds__(256) void ce_final(const float* __restrict__ ws,
                                                float* __restrict__ out) {
    const float* xt = ws;
    const float* part = ws + NROW;
    float acc = 0.0f;
    for (int b = threadIdx.x; b < NROW; b += 256) {
        float S = part[2 * b] + part[2 * b + 1];
        acc += __logf(S) - xt[b];
    }
    for (int off = 32; off; off >>= 1) acc += __shfl_down(acc, off, 64);
    __shared__ float sacc[4];
    if ((threadIdx.x & 63) == 0) sacc[threadIdx.x >> 6] = acc;
    __syncthreads();
    if (threadIdx.x == 0) {
        out[0] = ((sacc[0] + sacc[1]) + (sacc[2] + sacc[3])) / (float)NROW;
    }
}

extern "C" void kernel_launch(void* const* d_in, const int* in_sizes, int n_in,
                              void* d_out, int out_size, void* d_ws, size_t ws_size,
                              hipStream_t stream) {
    const float* pred = (const float*)d_in[0];
    const int* target = (const int*)d_in[1];
    float* out = (float*)d_out;
    float* ws = (float*)d_ws;

    ce_probe8<<<2 * NROW, 256, 0, stream>>>(pred, target, ws, 1777, 0.0f);
    ce_final<<<1, 256, 0, stream>>>(ws, out);
}